// Round 1
// baseline (2343.849 us; speedup 1.0000x reference)
//
#include <hip/hip_runtime.h>
#include <math.h>

#define NPTS   262144      // B * NPB
#define NPB_   131072
#define CIN_   96
#define COUT_  96
#define K3_    27
#define EPS_   1e-5f

// ---------------------------------------------------------------------------
// Kernel 1: sparse 3^3 conv  h[n,co] = sum_k sum_ci x[nbr[n,k], ci] * W[k,ci,co]
// block = 256 threads, 64 points. thread t: p = t>>2 (point), cb = t&3 (24-ch slab)
// x rows gathered into LDS per k; W[k] staged in LDS in two 48-row halves.
// ---------------------------------------------------------------------------
__global__ __launch_bounds__(256) void conv_kernel(
    const float* __restrict__ x, const int* __restrict__ nbr,
    const float* __restrict__ W, float* __restrict__ hout)
{
    __shared__ float x_lds[64][100];        // padded: stride 100 -> <=2-way conflicts
    __shared__ float w_lds[48 * 96];        // one ci-half of W[k]
    __shared__ int   nbr_lds[64 * 27];

    const int tid = threadIdx.x;
    const int base = blockIdx.x * 64;
    const int p   = tid >> 2;
    const int cb  = tid & 3;
    const int co0 = cb * 24;

    // stage neighbor indices for these 64 points (coalesced)
    for (int i = tid; i < 64 * 27; i += 256)
        nbr_lds[i] = nbr[base * 27 + i];

    float4 acc[6];
    #pragma unroll
    for (int u = 0; u < 6; ++u) acc[u] = make_float4(0.f, 0.f, 0.f, 0.f);

    __syncthreads();

    for (int k = 0; k < K3_; ++k) {
        // ---- stage gathered x rows (each thread: 24 floats of its point's row)
        {
            int idx = nbr_lds[p * 27 + k];
            float4* dst = (float4*)&x_lds[p][co0];
            if (idx >= 0) {
                const float4* src = (const float4*)(x + (long)idx * 96 + co0);
                #pragma unroll
                for (int j = 0; j < 6; ++j) dst[j] = src[j];
            } else {
                #pragma unroll
                for (int j = 0; j < 6; ++j) dst[j] = make_float4(0.f,0.f,0.f,0.f);
            }
        }
        #pragma unroll 1
        for (int h = 0; h < 2; ++h) {
            // ---- stage W[k][h*48 .. h*48+47][:]  (4608 floats = 1152 float4)
            {
                const float4* wsrc = (const float4*)(W + (long)k * 9216 + h * 4608);
                for (int i = tid; i < 1152; i += 256)
                    ((float4*)w_lds)[i] = wsrc[i];
            }
            __syncthreads();
            // ---- compute: acc[co0..co0+23] += x[p][h*48+ci] * W[ci][co]
            #pragma unroll 2
            for (int ci4 = 0; ci4 < 48; ci4 += 4) {
                float4 xv = *(const float4*)&x_lds[p][h * 48 + ci4];
                float xarr[4] = {xv.x, xv.y, xv.z, xv.w};
                #pragma unroll
                for (int j = 0; j < 4; ++j) {
                    const float xs = xarr[j];
                    const float* wrow = &w_lds[(ci4 + j) * 96 + co0];
                    #pragma unroll
                    for (int u = 0; u < 6; ++u) {
                        float4 wv = *(const float4*)&wrow[u * 4];
                        acc[u].x = fmaf(xs, wv.x, acc[u].x);
                        acc[u].y = fmaf(xs, wv.y, acc[u].y);
                        acc[u].z = fmaf(xs, wv.z, acc[u].z);
                        acc[u].w = fmaf(xs, wv.w, acc[u].w);
                    }
                }
            }
            __syncthreads();
        }
    }

    // write h (fully coalesced: block covers contiguous 64*96 floats)
    float4* out4 = (float4*)(hout + (long)(base + p) * 96 + co0);
    #pragma unroll
    for (int u = 0; u < 6; ++u) out4[u] = acc[u];
}

// ---------------------------------------------------------------------------
// Kernel 2: per-scene per-channel partial sum / sumsq / max over h
// grid = 512 blocks (256 per scene, 512 rows each); 96 active threads
// ---------------------------------------------------------------------------
__global__ __launch_bounds__(128) void stats_kernel(
    const float* __restrict__ h, float* __restrict__ partials)
{
    const int b2 = blockIdx.x;            // 0..511
    const int scene = b2 >> 8;
    const int chunk = b2 & 255;
    const long row0 = (long)scene * NPB_ + (long)chunk * 512;
    const int t = threadIdx.x;
    if (t < 96) {
        float s = 0.f, q = 0.f, m = -INFINITY;
        const float* pbase = h + row0 * 96 + t;
        for (int r = 0; r < 512; ++r) {
            float v = pbase[(long)r * 96];
            s += v;
            q = fmaf(v, v, q);
            m = fmaxf(m, v);
        }
        float* outp = partials + (long)b2 * 288;
        outp[t]       = s;
        outp[96 + t]  = q;
        outp[192 + t] = m;
    }
}

// ---------------------------------------------------------------------------
// Kernel 3: reduce partials -> scene stats; channel-attention MLP + softmax;
// analytic BN stats. Single block.
// smal layout (floats): [0..191] attn[2][96], [192..287] mu, [288..383] invstd
// ---------------------------------------------------------------------------
__global__ __launch_bounds__(128) void attn_kernel(
    const float* __restrict__ partials,
    const float* __restrict__ w1, const float* __restrict__ bias1,
    const float* __restrict__ w2, const float* __restrict__ bias2,
    float* __restrict__ smal)
{
    __shared__ float Sb[2][96], Qb[2][96];
    __shared__ float vecs[4][96];     // mean0, max0, mean1, max1
    __shared__ float hid[4][48];
    __shared__ float logit[2][96];
    __shared__ float attn[2][96];
    __shared__ float red[2][2];       // per scene: max, expsum
    const int t = threadIdx.x;

    for (int b = 0; b < 2; ++b) {
        if (t < 96) {
            float s = 0.f, q = 0.f, m = -INFINITY;
            const float* pp = partials + (long)b * 256 * 288;
            for (int i = 0; i < 256; ++i) {
                s += pp[i * 288 + t];
                q += pp[i * 288 + 96 + t];
                m = fmaxf(m, pp[i * 288 + 192 + t]);
            }
            Sb[b][t] = s;
            Qb[b][t] = q;
            vecs[2 * b][t]     = s * (1.0f / (float)NPB_);
            vecs[2 * b + 1][t] = m;
        }
    }
    __syncthreads();

    // hidden layer 96 -> 48, relu
    for (int v = 0; v < 4; ++v) {
        if (t < 48) {
            float a = bias1[t];
            for (int c = 0; c < 96; ++c) a = fmaf(vecs[v][c], w1[c * 48 + t], a);
            hid[v][t] = fmaxf(a, 0.f);
        }
    }
    __syncthreads();

    // output layer 48 -> 96, relu; logits = mlp(mean) + mlp(max)
    if (t < 96) {
        for (int b = 0; b < 2; ++b) {
            float om = bias2[t], ox = bias2[t];
            for (int j = 0; j < 48; ++j) {
                om = fmaf(hid[2 * b][j],     w2[j * 96 + t], om);
                ox = fmaf(hid[2 * b + 1][j], w2[j * 96 + t], ox);
            }
            logit[b][t] = fmaxf(om, 0.f) + fmaxf(ox, 0.f);
        }
    }
    __syncthreads();

    // softmax over channels, per scene (serial on 2 threads; 96 elems -> trivial)
    if (t < 2) {
        float mx = -INFINITY;
        for (int c = 0; c < 96; ++c) mx = fmaxf(mx, logit[t][c]);
        float s = 0.f;
        for (int c = 0; c < 96; ++c) s += __expf(logit[t][c] - mx);
        red[t][0] = mx;
        red[t][1] = s;
    }
    __syncthreads();
    if (t < 96) {
        for (int b = 0; b < 2; ++b)
            attn[b][t] = __expf(logit[b][t] - red[b][0]) / red[b][1];
    }
    __syncthreads();

    // analytic BN stats over out = h * attn (per scene broadcast)
    if (t < 96) {
        float a0 = attn[0][t], a1 = attn[1][t];
        const float invN = 1.0f / (float)NPTS;
        float mu = (a0 * Sb[0][t] + a1 * Sb[1][t]) * invN;
        float e2 = (a0 * a0 * Qb[0][t] + a1 * a1 * Qb[1][t]) * invN;
        float var = e2 - mu * mu;
        smal[t]        = a0;
        smal[96 + t]   = a1;
        smal[192 + t]  = mu;
        smal[288 + t]  = rsqrtf(var + EPS_);
    }
}

// ---------------------------------------------------------------------------
// Kernel 4: finalize (in place on d_out which holds h):
// out = relu( relu(gamma*(h*attn - mu)*invstd + beta) + x )
// ---------------------------------------------------------------------------
__global__ __launch_bounds__(256) void final_kernel(
    const float* __restrict__ x, const float* __restrict__ smal,
    const float* __restrict__ gamma, const float* __restrict__ beta,
    float* __restrict__ out)
{
    const int nq = NPTS * 24;                 // float4 quads
    const int sceneq = NPB_ * 24;
    for (int i = blockIdx.x * 256 + threadIdx.x; i < nq; i += gridDim.x * 256) {
        const int b = (i >= sceneq) ? 1 : 0;
        const int q = i % 24;                 // channel quad 0..23
        float4 h4 = ((const float4*)out)[i];
        float4 x4 = ((const float4*)x)[i];
        float4 a4  = ((const float4*)(smal + b * 96))[q];
        float4 mu4 = ((const float4*)(smal + 192))[q];
        float4 is4 = ((const float4*)(smal + 288))[q];
        float4 g4  = ((const float4*)gamma)[q];
        float4 be4 = ((const float4*)beta)[q];
        float4 r;
        r.x = fmaxf(fmaxf(fmaf((h4.x * a4.x - mu4.x) * is4.x, g4.x, be4.x), 0.f) + x4.x, 0.f);
        r.y = fmaxf(fmaxf(fmaf((h4.y * a4.y - mu4.y) * is4.y, g4.y, be4.y), 0.f) + x4.y, 0.f);
        r.z = fmaxf(fmaxf(fmaf((h4.z * a4.z - mu4.z) * is4.z, g4.z, be4.z), 0.f) + x4.z, 0.f);
        r.w = fmaxf(fmaxf(fmaf((h4.w * a4.w - mu4.w) * is4.w, g4.w, be4.w), 0.f) + x4.w, 0.f);
        ((float4*)out)[i] = r;
    }
}

// ---------------------------------------------------------------------------
extern "C" void kernel_launch(void* const* d_in, const int* in_sizes, int n_in,
                              void* d_out, int out_size, void* d_ws, size_t ws_size,
                              hipStream_t stream)
{
    const float* x     = (const float*)d_in[0];
    const int*   nbr   = (const int*)  d_in[1];
    const float* W     = (const float*)d_in[2];
    const float* w1    = (const float*)d_in[3];
    const float* b1    = (const float*)d_in[4];
    const float* w2    = (const float*)d_in[5];
    const float* b2    = (const float*)d_in[6];
    const float* gamma = (const float*)d_in[7];
    const float* beta  = (const float*)d_in[8];
    float* out = (float*)d_out;

    float* partials = (float*)d_ws;            // 512*288 floats = 576 KB
    float* smal     = partials + 512 * 288;    // 384 floats

    // h is materialized into d_out, then finalized in place.
    conv_kernel <<<NPTS / 64, 256, 0, stream>>>(x, nbr, W, out);
    stats_kernel<<<512, 128, 0, stream>>>(out, partials);
    attn_kernel <<<1, 128, 0, stream>>>(partials, w1, b1, w2, b2, smal);
    final_kernel<<<2048, 256, 0, stream>>>(x, smal, gamma, beta, out);
}

// Round 2
// 516.982 us; speedup vs baseline: 4.5337x; 4.5337x over previous
//
#include <hip/hip_runtime.h>
#include <math.h>

#define NPTS   262144      // B * NPB
#define NPB_   131072
#define K3_    27
#define EPS_   1e-5f
#define WTAP   36864       // bytes per tap in wt: hi matrix 18432 + lo matrix 18432

typedef __attribute__((ext_vector_type(8)))  short  short8;
typedef __attribute__((ext_vector_type(8)))  __bf16 bf16x8;
typedef __attribute__((ext_vector_type(16))) float  f32x16;

__device__ __forceinline__ unsigned short f2bf(float f) {   // RNE float -> bf16 bits
    unsigned u = __builtin_bit_cast(unsigned, f);
    u += 0x7FFFu + ((u >> 16) & 1u);
    return (unsigned short)(u >> 16);
}
__device__ __forceinline__ float bf2f(unsigned short h) {
    unsigned u = ((unsigned)h) << 16;
    return __builtin_bit_cast(float, u);
}

__device__ __forceinline__ void gload_lds16(const void* g, void* l) {
    __builtin_amdgcn_global_load_lds(
        (const __attribute__((address_space(1))) unsigned int*)g,
        (__attribute__((address_space(3))) unsigned int*)l, 16, 0, 0);
}

// ---------------------------------------------------------------------------
// Kernel 0: split W into bf16 hi/lo, transposed to [co][ci], XOR-swizzled so a
// linear global_load_lds staging lands in swizzled LDS layout (rule: inverse-
// swizzled source + swizzled read).
// wt layout: tap k at k*36864; hi matrix bytes [0,18432), lo at +18432.
// element (co,ci): byte off = (co*192 + ci*2) ^ ((co&7)<<4)
// ---------------------------------------------------------------------------
__global__ __launch_bounds__(256) void wprep_kernel(
    const float* __restrict__ W, char* __restrict__ wt)
{
    int id = blockIdx.x * 256 + threadIdx.x;
    if (id >= 27 * 96 * 96) return;
    int k = id / 9216, r = id % 9216, co = r / 96, ci = r % 96;
    float w = W[k * 9216 + ci * 96 + co];
    unsigned short hb = f2bf(w);
    unsigned short lb = f2bf(w - bf2f(hb));
    int swz = (co * 192 + ci * 2) ^ ((co & 7) << 4);
    char* base = wt + (long)k * WTAP;
    *(unsigned short*)(base + swz)          = hb;
    *(unsigned short*)(base + 18432 + swz)  = lb;
}

// ---------------------------------------------------------------------------
// Kernel 1: sparse conv via 32x32x16 bf16 MFMA, 3-term hi/lo split.
// block = 256 thr = 4 waves; wave owns 64 rows (2 M-subtiles of 32) x 96 cols
// (3 N-tiles of 32). W[k] staged in LDS (global_load_lds), A gathered
// global->reg with inline fp32->bf16 hi/lo split. Per-block channel stats
// (sum/sumsq/max) fused into epilogue.
// ---------------------------------------------------------------------------
__global__ __launch_bounds__(256, 2) void conv_mfma(
    const float* __restrict__ x, const int* __restrict__ nbr,
    const char* __restrict__ wt, float* __restrict__ hout,
    float* __restrict__ partials)
{
    __shared__ __align__(16) char wlds[WTAP];
    __shared__ float red[4][3][32][3];

    const int tid = threadIdx.x;
    const int wv  = tid >> 6;
    const int l   = tid & 63;
    const int l31 = l & 31;
    const int lh  = l >> 5;
    const int blockM = blockIdx.x * 256;
    const int row0 = blockM + wv * 64 + l31;
    const int row1 = row0 + 32;

    f32x16 acc[2][3] = {};

    const int xorv = (l31 & 7) << 4;
    int cobase[3];
    #pragma unroll
    for (int n = 0; n < 3; ++n) cobase[n] = (n * 32 + l31) * 192;

    int idx0 = nbr[row0 * 27];
    int idx1 = nbr[row1 * 27];

    #pragma unroll 1
    for (int k = 0; k < 27; ++k) {
        __syncthreads();                     // everyone done reading prev tap's W
        {   // stage W tap k: 36864 B = 256 thr * 9 * 16 B, linear
            const char* g = wt + (long)k * WTAP + tid * 16;
            char* lp = wlds + tid * 16;
            #pragma unroll
            for (int i = 0; i < 9; ++i)
                gload_lds16(g + i * 4096, lp + i * 4096);
        }

        float4 buf[2][2][2];                 // [parity][msub][quad]
        {   // A raw loads for kstep 0 (overlap with W staging)
            const float4* p0 = (const float4*)(x + (long)idx0 * 96 + lh * 8);
            const float4* p1 = (const float4*)(x + (long)idx1 * 96 + lh * 8);
            if (idx0 >= 0) { buf[0][0][0] = p0[0]; buf[0][0][1] = p0[1]; }
            else { buf[0][0][0] = make_float4(0,0,0,0); buf[0][0][1] = make_float4(0,0,0,0); }
            if (idx1 >= 0) { buf[0][1][0] = p1[0]; buf[0][1][1] = p1[1]; }
            else { buf[0][1][0] = make_float4(0,0,0,0); buf[0][1][1] = make_float4(0,0,0,0); }
        }
        __syncthreads();                     // W visible (vmcnt(0) drained at barrier)

        #pragma unroll
        for (int s = 0; s < 6; ++s) {
            if (s < 5) {                     // prefetch next kstep's A
                const int sp = s + 1;
                const float4* p0 = (const float4*)(x + (long)idx0 * 96 + sp * 16 + lh * 8);
                const float4* p1 = (const float4*)(x + (long)idx1 * 96 + sp * 16 + lh * 8);
                if (idx0 >= 0) { buf[sp & 1][0][0] = p0[0]; buf[sp & 1][0][1] = p0[1]; }
                else { buf[sp & 1][0][0] = make_float4(0,0,0,0); buf[sp & 1][0][1] = make_float4(0,0,0,0); }
                if (idx1 >= 0) { buf[sp & 1][1][0] = p1[0]; buf[sp & 1][1][1] = p1[1]; }
                else { buf[sp & 1][1][0] = make_float4(0,0,0,0); buf[sp & 1][1][1] = make_float4(0,0,0,0); }
            }
            // convert current kstep's A to hi/lo bf16 frags
            bf16x8 ah[2], al[2];
            #pragma unroll
            for (int ms = 0; ms < 2; ++ms) {
                float a[8] = { buf[s & 1][ms][0].x, buf[s & 1][ms][0].y,
                               buf[s & 1][ms][0].z, buf[s & 1][ms][0].w,
                               buf[s & 1][ms][1].x, buf[s & 1][ms][1].y,
                               buf[s & 1][ms][1].z, buf[s & 1][ms][1].w };
                short8 hs, ls;
                #pragma unroll
                for (int j = 0; j < 8; ++j) {
                    unsigned short hb = f2bf(a[j]);
                    hs[j] = (short)hb;
                    ls[j] = (short)f2bf(a[j] - bf2f(hb));
                }
                ah[ms] = __builtin_bit_cast(bf16x8, hs);
                al[ms] = __builtin_bit_cast(bf16x8, ls);
            }
            const int cioff2 = s * 32 + lh * 16;
            #pragma unroll
            for (int n = 0; n < 3; ++n) {
                const int a  = (cobase[n] + cioff2) ^ xorv;
                bf16x8 bh = __builtin_bit_cast(bf16x8, *(const short8*)(wlds + a));
                bf16x8 bl = __builtin_bit_cast(bf16x8, *(const short8*)(wlds + 18432 + a));
                #pragma unroll
                for (int ms = 0; ms < 2; ++ms) {
                    acc[ms][n] = __builtin_amdgcn_mfma_f32_32x32x16_bf16(ah[ms], bh, acc[ms][n], 0, 0, 0);
                    acc[ms][n] = __builtin_amdgcn_mfma_f32_32x32x16_bf16(ah[ms], bl, acc[ms][n], 0, 0, 0);
                    acc[ms][n] = __builtin_amdgcn_mfma_f32_32x32x16_bf16(al[ms], bh, acc[ms][n], 0, 0, 0);
                }
            }
        }
        if (k < 26) {                        // prefetch next tap's gather indices
            idx0 = nbr[row0 * 27 + k + 1];
            idx1 = nbr[row1 * 27 + k + 1];
        }
    }

    // ---- write h (C/D layout: col = lane&31, row = (r&3) + 8*(r>>2) + 4*lh)
    #pragma unroll
    for (int ms = 0; ms < 2; ++ms)
        #pragma unroll
        for (int n = 0; n < 3; ++n)
            #pragma unroll
            for (int r = 0; r < 16; ++r) {
                int rw = (r & 3) + 8 * (r >> 2) + 4 * lh;
                hout[(long)(blockM + wv * 64 + ms * 32 + rw) * 96 + n * 32 + l31] = acc[ms][n][r];
            }

    // ---- fused per-block channel stats (sum / sumsq / max)
    float sv[3], qv[3], mv[3];
    #pragma unroll
    for (int n = 0; n < 3; ++n) { sv[n] = 0.f; qv[n] = 0.f; mv[n] = -INFINITY; }
    #pragma unroll
    for (int ms = 0; ms < 2; ++ms)
        #pragma unroll
        for (int n = 0; n < 3; ++n)
            #pragma unroll
            for (int r = 0; r < 16; ++r) {
                float v = acc[ms][n][r];
                sv[n] += v;
                qv[n] = fmaf(v, v, qv[n]);
                mv[n] = fmaxf(mv[n], v);
            }
    #pragma unroll
    for (int n = 0; n < 3; ++n) {            // combine lane l with l+32 (same col)
        sv[n] += __shfl_xor(sv[n], 32);
        qv[n] += __shfl_xor(qv[n], 32);
        mv[n] = fmaxf(mv[n], __shfl_xor(mv[n], 32));
    }
    if (lh == 0) {
        #pragma unroll
        for (int n = 0; n < 3; ++n) {
            red[wv][n][l31][0] = sv[n];
            red[wv][n][l31][1] = qv[n];
            red[wv][n][l31][2] = mv[n];
        }
    }
    __syncthreads();
    if (tid < 96) {                           // channel = tid
        int n = tid >> 5, c = tid & 31;
        float S = 0.f, Q = 0.f, M = -INFINITY;
        #pragma unroll
        for (int w = 0; w < 4; ++w) {
            S += red[w][n][c][0];
            Q += red[w][n][c][1];
            M = fmaxf(M, red[w][n][c][2]);
        }
        float* op = partials + (long)blockIdx.x * 288;
        op[tid] = S; op[96 + tid] = Q; op[192 + tid] = M;
    }
}

// ---------------------------------------------------------------------------
// Kernel 2: reduce partials -> scene stats; attention MLP + softmax; analytic
// BN stats. Single block.
// smal: [0..95] attn scene0, [96..191] attn scene1, [192..287] mu, [288..383] invstd
// ---------------------------------------------------------------------------
__global__ __launch_bounds__(128) void attn_kernel(
    const float* __restrict__ partials,
    const float* __restrict__ w1, const float* __restrict__ bias1,
    const float* __restrict__ w2, const float* __restrict__ bias2,
    float* __restrict__ smal)
{
    __shared__ float Sb[2][96], Qb[2][96];
    __shared__ float vecs[4][96];
    __shared__ float hid[4][48];
    __shared__ float logit[2][96];
    __shared__ float attn[2][96];
    __shared__ float red2[2][2];
    const int t = threadIdx.x;

    for (int b = 0; b < 2; ++b) {
        if (t < 96) {
            float s = 0.f, q = 0.f, m = -INFINITY;
            const float* pp = partials + (long)b * 512 * 288;
            for (int i = 0; i < 512; ++i) {
                s += pp[i * 288 + t];
                q += pp[i * 288 + 96 + t];
                m = fmaxf(m, pp[i * 288 + 192 + t]);
            }
            Sb[b][t] = s;
            Qb[b][t] = q;
            vecs[2 * b][t]     = s * (1.0f / (float)NPB_);
            vecs[2 * b + 1][t] = m;
        }
    }
    __syncthreads();

    for (int v = 0; v < 4; ++v) {
        if (t < 48) {
            float a = bias1[t];
            for (int c = 0; c < 96; ++c) a = fmaf(vecs[v][c], w1[c * 48 + t], a);
            hid[v][t] = fmaxf(a, 0.f);
        }
    }
    __syncthreads();

    if (t < 96) {
        for (int b = 0; b < 2; ++b) {
            float om = bias2[t], ox = bias2[t];
            for (int j = 0; j < 48; ++j) {
                om = fmaf(hid[2 * b][j],     w2[j * 96 + t], om);
                ox = fmaf(hid[2 * b + 1][j], w2[j * 96 + t], ox);
            }
            logit[b][t] = fmaxf(om, 0.f) + fmaxf(ox, 0.f);
        }
    }
    __syncthreads();

    if (t < 2) {
        float mx = -INFINITY;
        for (int c = 0; c < 96; ++c) mx = fmaxf(mx, logit[t][c]);
        float s = 0.f;
        for (int c = 0; c < 96; ++c) s += __expf(logit[t][c] - mx);
        red2[t][0] = mx;
        red2[t][1] = s;
    }
    __syncthreads();
    if (t < 96) {
        for (int b = 0; b < 2; ++b)
            attn[b][t] = __expf(logit[b][t] - red2[b][0]) / red2[b][1];
    }
    __syncthreads();

    if (t < 96) {
        float a0 = attn[0][t], a1 = attn[1][t];
        const float invN = 1.0f / (float)NPTS;
        float mu = (a0 * Sb[0][t] + a1 * Sb[1][t]) * invN;
        float e2 = (a0 * a0 * Qb[0][t] + a1 * a1 * Qb[1][t]) * invN;
        float var = e2 - mu * mu;
        smal[t]       = a0;
        smal[96 + t]  = a1;
        smal[192 + t] = mu;
        smal[288 + t] = rsqrtf(var + EPS_);
    }
}

// ---------------------------------------------------------------------------
// Kernel 3: finalize in place on d_out (holds h):
// out = relu( relu(gamma*(h*attn - mu)*invstd + beta) + x )
// ---------------------------------------------------------------------------
__global__ __launch_bounds__(256) void final_kernel(
    const float* __restrict__ x, const float* __restrict__ smal,
    const float* __restrict__ gamma, const float* __restrict__ beta,
    float* __restrict__ out)
{
    const int nq = NPTS * 24;
    const int sceneq = NPB_ * 24;
    for (int i = blockIdx.x * 256 + threadIdx.x; i < nq; i += gridDim.x * 256) {
        const int b = (i >= sceneq) ? 1 : 0;
        const int q = i % 24;
        float4 h4 = ((const float4*)out)[i];
        float4 x4 = ((const float4*)x)[i];
        float4 a4  = ((const float4*)(smal + b * 96))[q];
        float4 mu4 = ((const float4*)(smal + 192))[q];
        float4 is4 = ((const float4*)(smal + 288))[q];
        float4 g4  = ((const float4*)gamma)[q];
        float4 be4 = ((const float4*)beta)[q];
        float4 r;
        r.x = fmaxf(fmaxf(fmaf((h4.x * a4.x - mu4.x) * is4.x, g4.x, be4.x), 0.f) + x4.x, 0.f);
        r.y = fmaxf(fmaxf(fmaf((h4.y * a4.y - mu4.y) * is4.y, g4.y, be4.y), 0.f) + x4.y, 0.f);
        r.z = fmaxf(fmaxf(fmaf((h4.z * a4.z - mu4.z) * is4.z, g4.z, be4.z), 0.f) + x4.z, 0.f);
        r.w = fmaxf(fmaxf(fmaf((h4.w * a4.w - mu4.w) * is4.w, g4.w, be4.w), 0.f) + x4.w, 0.f);
        ((float4*)out)[i] = r;
    }
}

// ---------------------------------------------------------------------------
extern "C" void kernel_launch(void* const* d_in, const int* in_sizes, int n_in,
                              void* d_out, int out_size, void* d_ws, size_t ws_size,
                              hipStream_t stream)
{
    const float* x     = (const float*)d_in[0];
    const int*   nbr   = (const int*)  d_in[1];
    const float* W     = (const float*)d_in[2];
    const float* w1    = (const float*)d_in[3];
    const float* b1    = (const float*)d_in[4];
    const float* w2    = (const float*)d_in[5];
    const float* b2    = (const float*)d_in[6];
    const float* gamma = (const float*)d_in[7];
    const float* beta  = (const float*)d_in[8];
    float* out = (float*)d_out;

    char*  wt       = (char*)d_ws;                        // 27*36864 = 995328 B
    float* partials = (float*)((char*)d_ws + 995328);     // 1024*288*4 = 1179648 B
    float* smal     = (float*)((char*)d_ws + 995328 + 1179648);  // 384 floats

    wprep_kernel<<<972, 256, 0, stream>>>(W, wt);
    conv_mfma   <<<1024, 256, 0, stream>>>(x, nbr, wt, out, partials);
    attn_kernel <<<1, 128, 0, stream>>>(partials, w1, b1, w2, b2, smal);
    final_kernel<<<2048, 256, 0, stream>>>(x, smal, gamma, beta, out);
}